// Round 4
// baseline (352.192 us; speedup 1.0000x reference)
//
#include <hip/hip_runtime.h>
#include <hip/hip_bf16.h>

// ---------------------------------------------------------------------------
// N=20000 nodes, D_MODEL=1024, D_FF=286 (pad 288), NUM_REL=2, E=320000.
//
// Pipeline:
//   norm = rmsnorm(x) -> bf16
//   proj[z] = norm @ W_z   z in {root, rel0, rel1}   (bf16 MFMA, z-fastest,
//             XCD-grouped so z-triples share one L2; single-buffer staging;
//             slot-XOR LDS swizzle -> conflict-free frag reads)
//   counting-sort edges by dst (hist -> scan -> cursor scatter)
//   per-dst wave: gather+sum proj_rel rows (unroll 4, branchless), mean+root
//                 +bias+ELU -> y2 (bf16)
//   out = hidden + y2 @ wo  (bf16 MFMA, dbuf staging; epilogue LDS-transposes
//         acc so residual add + store run as full-line float4 nt ops)
// ---------------------------------------------------------------------------

typedef __bf16  bf16x8  __attribute__((ext_vector_type(8)));
typedef float   floatx4 __attribute__((ext_vector_type(4)));

#define NNODE   20000
#define DMODEL  1024
#define DFF     286
#define DFFP    288
#define NDW     144     // dwords per padded row
#define NPAIR   72      // uint2 per padded row

typedef __attribute__((address_space(1))) const void* gptr_t;
typedef __attribute__((address_space(3))) void*       lptr_t;

struct alignas(8) bf4 { __bf16 x, y, z, w; };

__device__ __forceinline__ float bflo(unsigned u) {
    union { unsigned u; float f; } c; c.u = u << 16; return c.f;
}
__device__ __forceinline__ float bfhi(unsigned u) {
    union { unsigned u; float f; } c; c.u = u & 0xffff0000u; return c.f;
}
__device__ __forceinline__ unsigned packbf(float a, float b) {
    union { __bf16 h[2]; unsigned u; } c;
    c.h[0] = (__bf16)a; c.h[1] = (__bf16)b; return c.u;
}
__device__ __forceinline__ float elu1(float v) {
    return v > 0.0f ? v : (expf(v) - 1.0f);
}

// ---------------------------------------------------------------------------
// K0: tiled transpose + cast fp32 [K][N] -> bf16 [Nout][Kout], zero-padded.
// ---------------------------------------------------------------------------
__global__ __launch_bounds__(256) void k_transpose_cast(
    const float* __restrict__ src, __bf16* __restrict__ dst,
    int K, int N, int Kout, int Nout)
{
    __shared__ float t[32][33];
    int tx = threadIdx.x & 31, ty = threadIdx.x >> 5;
    int k0 = blockIdx.x * 32, n0 = blockIdx.y * 32;
    #pragma unroll
    for (int r = 0; r < 4; ++r) {
        int k = k0 + ty + r * 8, n = n0 + tx;
        t[ty + r * 8][tx] = (k < K && n < N) ? src[(size_t)k * N + n] : 0.0f;
    }
    __syncthreads();
    #pragma unroll
    for (int r = 0; r < 4; ++r) {
        int n = n0 + ty + r * 8, k = k0 + tx;
        if (n < Nout && k < Kout) dst[(size_t)n * Kout + k] = (__bf16)t[tx][ty + r * 8];
    }
}

// ---------------------------------------------------------------------------
// K1: T5 RMSNorm, one block (256 thr) per row, float4 loads, bf16 out.
// ---------------------------------------------------------------------------
__global__ __launch_bounds__(256) void k_rmsnorm(
    const float* __restrict__ x, const float* __restrict__ w,
    __bf16* __restrict__ out)
{
    int row = blockIdx.x;
    int t = threadIdx.x;
    float4 v = reinterpret_cast<const float4*>(x + (size_t)row * DMODEL)[t];
    float ss = v.x * v.x + v.y * v.y + v.z * v.z + v.w * v.w;
    #pragma unroll
    for (int off = 32; off; off >>= 1) ss += __shfl_down(ss, off, 64);
    __shared__ float red[4];
    int lane = t & 63, wv = t >> 6;
    if (lane == 0) red[wv] = ss;
    __syncthreads();
    float tot = red[0] + red[1] + red[2] + red[3];
    float scale = rsqrtf(tot * (1.0f / (float)DMODEL) + 1e-6f);
    float4 wv4 = reinterpret_cast<const float4*>(w)[t];
    bf4 o;
    o.x = (__bf16)(v.x * scale * wv4.x);
    o.y = (__bf16)(v.y * scale * wv4.y);
    o.z = (__bf16)(v.z * scale * wv4.z);
    o.w = (__bf16)(v.w * scale * wv4.w);
    reinterpret_cast<bf4*>(out + (size_t)row * DMODEL)[t] = o;
}

// ---------------------------------------------------------------------------
// K2: GEMM1  proj[z] = norm @ B_z.   A:[20000][1024] bf16, B^T:[288][1024].
// Block = 128(M) x 288(N) for one z; 1-D grid, z fastest; bijective XCD
// swizzle groups z-triples on one XCD (A L2 reuse).
// 4 waves 2x2; wave-tile 64x144 = 4x9 MFMAs.
// SINGLE-buffered global_load_lds staging (stage -> barrier -> compute ->
// barrier): R3's merged-barrier dbuf regressed 52->65us because hipcc's
// vmcnt(0)-before-barrier drains the prefetch every iter anyway; the
// 2-barrier form lets cross-block waves overlap the stage wait (m114).
// LDS slot-XOR swizzle: stored 16B slot = logical ^ ((row>>1)&3), applied
// via pre-swizzled per-lane GLOBAL source (dest stays linear) and matching
// XOR on the ds_read address -> conflict-free frag reads.
// ---------------------------------------------------------------------------
__global__ __launch_bounds__(256, 2) void k_gemm1(
    const __bf16* __restrict__ A, const __bf16* __restrict__ Broot,
    const __bf16* __restrict__ Brel, __bf16* __restrict__ P)
{
    // bijective XCD swizzle (nwg = 471, not a multiple of 8)
    const int nwg = gridDim.x;
    const int q = nwg >> 3, r = nwg & 7;
    const int xcd = blockIdx.x & 7, sub = blockIdx.x >> 3;
    const int bid = (xcd < r ? xcd * (q + 1) : r * (q + 1) + (xcd - r) * q) + sub;

    const int mt = bid / 3, mz = bid - mt * 3;
    const __bf16* B = (mz == 0) ? Broot : (Brel + (size_t)(mz - 1) * DFFP * DMODEL);
    __bf16* out = P + (size_t)mz * NNODE * DFFP;

    const int m0 = mt * 128;
    const int tid = threadIdx.x;
    const int lane = tid & 63, wave = tid >> 6;
    const int wm = wave >> 1, wn = wave & 1;
    const int quad = lane >> 4, l16 = lane & 15;

    __shared__ __align__(16) __bf16 As[128 * 32];   // 8 KB
    __shared__ __align__(16) __bf16 Bs[288 * 32];   // 18 KB

    floatx4 zero = {0.f, 0.f, 0.f, 0.f};
    floatx4 acc[4][9];
    #pragma unroll
    for (int i = 0; i < 4; ++i)
        #pragma unroll
        for (int j = 0; j < 9; ++j) acc[i][j] = zero;

    const int crow = lane >> 2;                              // row within 16-row chunk
    const int ccol = ((lane & 3) ^ ((lane >> 3) & 3)) * 8;   // swizzled K-slot source
    const int sq   = (quad ^ ((l16 >> 1) & 3)) * 8;          // swizzled K-slot read

    for (int k0 = 0; k0 < DMODEL; k0 += 32) {
        #pragma unroll
        for (int ii = 0; ii < 7; ++ii) {
            int c = wave + ii * 4;
            if (c < 8) {
                int row = c * 16 + crow;
                int grow = m0 + row; if (grow > NNODE - 1) grow = NNODE - 1;
                __builtin_amdgcn_global_load_lds(
                    (gptr_t)(A + (size_t)grow * DMODEL + k0 + ccol),
                    (lptr_t)(As + c * 512), 16, 0, 0);
            } else if (c < 26) {
                int nrow = (c - 8) * 16 + crow;
                __builtin_amdgcn_global_load_lds(
                    (gptr_t)(B + (size_t)nrow * DMODEL + k0 + ccol),
                    (lptr_t)(Bs + (c - 8) * 512), 16, 0, 0);
            }
        }
        __syncthreads();
        bf16x8 af[4], bq[9];
        #pragma unroll
        for (int i = 0; i < 4; ++i)
            af[i] = *reinterpret_cast<const bf16x8*>(As + (wm * 64 + i * 16 + l16) * 32 + sq);
        #pragma unroll
        for (int j = 0; j < 9; ++j)
            bq[j] = *reinterpret_cast<const bf16x8*>(Bs + (wn * 144 + j * 16 + l16) * 32 + sq);
        #pragma unroll
        for (int i = 0; i < 4; ++i)
            #pragma unroll
            for (int j = 0; j < 9; ++j)
                acc[i][j] = __builtin_amdgcn_mfma_f32_16x16x32_bf16(af[i], bq[j], acc[i][j], 0, 0, 0);
        __syncthreads();
    }
    #pragma unroll
    for (int i = 0; i < 4; ++i) {
        int rbase = m0 + wm * 64 + i * 16 + quad * 4;
        #pragma unroll
        for (int j = 0; j < 9; ++j) {
            int col = wn * 144 + j * 16 + l16;
            #pragma unroll
            for (int rr = 0; rr < 4; ++rr) {
                int row = rbase + rr;
                if (row < NNODE) out[(size_t)row * DFFP + col] = (__bf16)acc[i][j][rr];
            }
        }
    }
}

// ---------------------------------------------------------------------------
// K3a: histogram of edges by dst.
// ---------------------------------------------------------------------------
__global__ __launch_bounds__(256) void k_hist(
    const int* __restrict__ ei, int* __restrict__ bcnt, int E)
{
    int t = blockIdx.x * 256 + threadIdx.x;
    if (t < E) atomicAdd(&bcnt[ei[E + t]], 1);
}

// ---------------------------------------------------------------------------
// K3b: exclusive scan over 20000 bucket counts (single block, 1024 thr).
// ---------------------------------------------------------------------------
__global__ __launch_bounds__(1024) void k_scan(
    const int* __restrict__ bcnt, int* __restrict__ boff, int* __restrict__ bcur)
{
    const int CH = 20;
    __shared__ int s[1024];
    int t = threadIdx.x;
    int base = t * CH;
    int loc[CH];
    int sum = 0;
    #pragma unroll
    for (int i = 0; i < CH; ++i) {
        int idx = base + i;
        int v = (idx < NNODE) ? bcnt[idx] : 0;
        loc[i] = sum; sum += v;
    }
    s[t] = sum;
    __syncthreads();
    for (int off = 1; off < 1024; off <<= 1) {
        int v = (t >= off) ? s[t - off] : 0;
        __syncthreads();
        s[t] += v;
        __syncthreads();
    }
    int prev = (t == 0) ? 0 : s[t - 1];
    #pragma unroll
    for (int i = 0; i < CH; ++i) {
        int idx = base + i;
        if (idx < NNODE) { int o = prev + loc[i]; boff[idx] = o; bcur[idx] = o; }
    }
    if (t == 1023) boff[NNODE] = s[1023];
}

// ---------------------------------------------------------------------------
// K3c: scatter edges into sorted order; payload = src | (r<<20).
// ---------------------------------------------------------------------------
__global__ __launch_bounds__(256) void k_scatter_idx(
    const int* __restrict__ ei, const int* __restrict__ et,
    int* __restrict__ bcur, int* __restrict__ sorted, int E)
{
    int t = blockIdx.x * 256 + threadIdx.x;
    if (t >= E) return;
    int src = ei[t], dst = ei[E + t], r = et[t];
    int pos = atomicAdd(&bcur[dst], 1);
    sorted[pos] = src | (r << 20);
}

// ---------------------------------------------------------------------------
// K4: segment reduce + epilogue. One wave per dst node; uint2 gathers,
// edge loop unrolled x4 (8 gathers in flight), branchless accumulate.
// ---------------------------------------------------------------------------
__global__ __launch_bounds__(256) void k_reduce(
    const int* __restrict__ boff, const int* __restrict__ sorted,
    const __bf16* __restrict__ proj, const float* __restrict__ bias,
    __bf16* __restrict__ y2)
{
    int b = blockIdx.x * 4 + (threadIdx.x >> 6);
    int lane = threadIdx.x & 63;
    int start = boff[b], end = boff[b + 1];
    bool t8 = lane < 8;

    const uint2* base1 = reinterpret_cast<const uint2*>(proj + (size_t)NNODE * DFFP);
    const size_t relstride = (size_t)NNODE * NPAIR;

    float a0[4] = {0.f, 0.f, 0.f, 0.f}, b0a[4] = {0.f, 0.f, 0.f, 0.f};
    float a1[4] = {0.f, 0.f, 0.f, 0.f}, b1a[4] = {0.f, 0.f, 0.f, 0.f};
    float c0 = 0.f, c1 = 0.f;
    uint2 zz; zz.x = 0u; zz.y = 0u;

    int e = start;
    for (; e + 4 <= end; e += 4) {
        uint2 x[4], y[4]; float w1[4];
        #pragma unroll
        for (int u = 0; u < 4; ++u) {
            int p = sorted[e + u];
            int ri = p >> 20;
            w1[u] = (float)ri;
            const uint2* row = base1 + (size_t)(p & 0xFFFFF) * NPAIR + (ri ? relstride : 0);
            x[u] = row[lane];
            y[u] = t8 ? row[64 + lane] : zz;
        }
        #pragma unroll
        for (int u = 0; u < 4; ++u) {
            float W1 = w1[u], W0 = 1.0f - W1;
            c0 += W0; c1 += W1;
            float v0 = bflo(x[u].x), v1 = bfhi(x[u].x), v2 = bflo(x[u].y), v3 = bfhi(x[u].y);
            a0[0] += W0 * v0; a1[0] += W1 * v0;
            a0[1] += W0 * v1; a1[1] += W1 * v1;
            a0[2] += W0 * v2; a1[2] += W1 * v2;
            a0[3] += W0 * v3; a1[3] += W1 * v3;
            float u0 = bflo(y[u].x), u1 = bfhi(y[u].x), u2 = bflo(y[u].y), u3 = bfhi(y[u].y);
            b0a[0] += W0 * u0; b1a[0] += W1 * u0;
            b0a[1] += W0 * u1; b1a[1] += W1 * u1;
            b0a[2] += W0 * u2; b1a[2] += W1 * u2;
            b0a[3] += W0 * u3; b1a[3] += W1 * u3;
        }
    }
    for (; e < end; ++e) {
        int p = sorted[e];
        int ri = p >> 20;
        float W1 = (float)ri, W0 = 1.0f - W1;
        const uint2* row = base1 + (size_t)(p & 0xFFFFF) * NPAIR + (ri ? relstride : 0);
        uint2 x = row[lane];
        uint2 y = t8 ? row[64 + lane] : zz;
        c0 += W0; c1 += W1;
        float v0 = bflo(x.x), v1 = bfhi(x.x), v2 = bflo(x.y), v3 = bfhi(x.y);
        a0[0] += W0 * v0; a1[0] += W1 * v0;
        a0[1] += W0 * v1; a1[1] += W1 * v1;
        a0[2] += W0 * v2; a1[2] += W1 * v2;
        a0[3] += W0 * v3; a1[3] += W1 * v3;
        float u0 = bflo(y.x), u1 = bfhi(y.x), u2 = bflo(y.y), u3 = bfhi(y.y);
        b0a[0] += W0 * u0; b1a[0] += W1 * u0;
        b0a[1] += W0 * u1; b1a[1] += W1 * u1;
        b0a[2] += W0 * u2; b1a[2] += W1 * u2;
        b0a[3] += W0 * u3; b1a[3] += W1 * u3;
    }

    float inv0 = 1.0f / fmaxf(c0, 1.0f);
    float inv1 = 1.0f / fmaxf(c1, 1.0f);

    const uint2* rootrow = reinterpret_cast<const uint2*>(proj) + (size_t)b * NPAIR;
    uint2* outrow = reinterpret_cast<uint2*>(y2) + (size_t)b * NPAIR;

    {
        uint2 rt = rootrow[lane];
        int f = 4 * lane;                 // max 255 < 286: no guard
        float v0 = bflo(rt.x) + bias[f]     + a0[0] * inv0 + a1[0] * inv1;
        float v1 = bfhi(rt.x) + bias[f + 1] + a0[1] * inv0 + a1[1] * inv1;
        float v2 = bflo(rt.y) + bias[f + 2] + a0[2] * inv0 + a1[2] * inv1;
        float v3 = bfhi(rt.y) + bias[f + 3] + a0[3] * inv0 + a1[3] * inv1;
        uint2 o; o.x = packbf(elu1(v0), elu1(v1)); o.y = packbf(elu1(v2), elu1(v3));
        outrow[lane] = o;
    }
    if (t8) {
        uint2 rt = rootrow[64 + lane];
        int f = 256 + 4 * lane;           // 256..287: guard vs 286
        float g0 = (f     < DFF) ? bias[f]     : 0.0f;
        float g1 = (f + 1 < DFF) ? bias[f + 1] : 0.0f;
        float g2 = (f + 2 < DFF) ? bias[f + 2] : 0.0f;
        float g3 = (f + 3 < DFF) ? bias[f + 3] : 0.0f;
        float v0 = bflo(rt.x) + g0 + b0a[0] * inv0 + b1a[0] * inv1;
        float v1 = bfhi(rt.x) + g1 + b0a[1] * inv0 + b1a[1] * inv1;
        float v2 = bflo(rt.y) + g2 + b0a[2] * inv0 + b1a[2] * inv1;
        float v3 = bfhi(rt.y) + g3 + b0a[3] * inv0 + b1a[3] * inv1;
        uint2 o; o.x = packbf(elu1(v0), elu1(v1)); o.y = packbf(elu1(v2), elu1(v3));
        outrow[64 + lane] = o;
    }
}

// ---------------------------------------------------------------------------
// K5: GEMM2  out = hidden + y2 @ wo.  A:[20000][288] bf16, B^T:[1024][288].
// Tile 128x128; 4 waves 2x2; wave-tile 64x64 = 4x4 MFMAs. 9 K-steps,
// double-buffered global_load_lds staging; slot-XOR LDS swizzle (as gemm1).
// Epilogue: per 16-row chunk, each wave scatters its acc into a private
// padded LDS region, reads back float4-per-lane, then residual add with
// float4 nontemporal loads/stores -> 256B contiguous, full-128B-line writes.
// ---------------------------------------------------------------------------
__global__ __launch_bounds__(256) void k_gemm2(
    const __bf16* __restrict__ A, const __bf16* __restrict__ Bt,
    const float* __restrict__ hidden, float* __restrict__ out)
{
    const int m0 = blockIdx.x * 128;
    const int n0 = blockIdx.y * 128;
    const int tid = threadIdx.x;
    const int lane = tid & 63, wave = tid >> 6;
    const int wm = wave >> 1, wn = wave & 1;
    const int quad = lane >> 4, l16 = lane & 15;

    __shared__ __align__(16) __bf16 As[2][128 * 32];   // 2 x 8 KB
    __shared__ __align__(16) __bf16 Bs[2][128 * 32];   // 2 x 8 KB

    floatx4 zero = {0.f, 0.f, 0.f, 0.f};
    floatx4 acc[4][4];
    #pragma unroll
    for (int i = 0; i < 4; ++i)
        #pragma unroll
        for (int j = 0; j < 4; ++j) acc[i][j] = zero;

    const int crow = lane >> 2;
    const int ccol = ((lane & 3) ^ ((lane >> 3) & 3)) * 8;   // swizzled K-slot source
    const int sq   = (quad ^ ((l16 >> 1) & 3)) * 8;          // swizzled K-slot read

    auto stage = [&](int kk, int buf) {
        #pragma unroll
        for (int ii = 0; ii < 4; ++ii) {
            int c = wave + ii * 4;
            if (c < 8) {
                int grow = m0 + c * 16 + crow; if (grow > NNODE - 1) grow = NNODE - 1;
                __builtin_amdgcn_global_load_lds(
                    (gptr_t)(A + (size_t)grow * DFFP + kk + ccol),
                    (lptr_t)(As[buf] + c * 512), 16, 0, 0);
            } else {
                int nrow = n0 + (c - 8) * 16 + crow;
                __builtin_amdgcn_global_load_lds(
                    (gptr_t)(Bt + (size_t)nrow * DFFP + kk + ccol),
                    (lptr_t)(Bs[buf] + (c - 8) * 512), 16, 0, 0);
            }
        }
    };

    stage(0, 0);
    __syncthreads();
    for (int ks = 0; ks < 9; ++ks) {
        int buf = ks & 1;
        if (ks < 8) stage((ks + 1) * 32, buf ^ 1);
        bf16x8 af[4], bq[4];
        #pragma unroll
        for (int i = 0; i < 4; ++i)
            af[i] = *reinterpret_cast<const bf16x8*>(As[buf] + (wm * 64 + i * 16 + l16) * 32 + sq);
        #pragma unroll
        for (int j = 0; j < 4; ++j)
            bq[j] = *reinterpret_cast<const bf16x8*>(Bs[buf] + (wn * 64 + j * 16 + l16) * 32 + sq);
        #pragma unroll
        for (int i = 0; i < 4; ++i)
            #pragma unroll
            for (int j = 0; j < 4; ++j)
                acc[i][j] = __builtin_amdgcn_mfma_f32_16x16x32_bf16(af[i], bq[j], acc[i][j], 0, 0, 0);
        __syncthreads();
    }

    // --- epilogue: LDS transpose -> float4 residual add, full-line nt I/O ---
    // Per-wave private scratch: 16 rows x 68 floats (padded) = 4352 B.
    // Waves 0,1 live in As (16 KB), waves 2,3 in Bs. No barriers needed:
    // each wave reads only its own region (post-loop __syncthreads already
    // ordered the last fragment reads before these writes).
    {
        float* smbase = reinterpret_cast<float*>(wave < 2 ? (__bf16*)As[0] : (__bf16*)Bs[0]);
        float* smw = smbase + (wave & 1) * 1088;         // 1088 = 16*68
        const int rsub = lane >> 4;                       // 0..3
        const int colf = n0 + wn * 64 + l16 * 4;          // 4 consecutive cols/lane
        #pragma unroll
        for (int i = 0; i < 4; ++i) {
            // scatter acc chunk (16 rows x 64 cols) into padded LDS
            #pragma unroll
            for (int j = 0; j < 4; ++j)
                #pragma unroll
                for (int rr = 0; rr < 4; ++rr)
                    smw[(quad * 4 + rr) * 68 + j * 16 + l16] = acc[i][j][rr];
            const int rbase = m0 + wm * 64 + i * 16;
            floatx4 h[4];
            #pragma unroll
            for (int k = 0; k < 4; ++k) {
                int row = rbase + k * 4 + rsub;
                if (row > NNODE - 1) row = NNODE - 1;
                h[k] = __builtin_nontemporal_load(
                    reinterpret_cast<const floatx4*>(hidden + (size_t)row * DMODEL + colf));
            }
            #pragma unroll
            for (int k = 0; k < 4; ++k) {
                int row = rbase + k * 4 + rsub;
                floatx4 v = *reinterpret_cast<const floatx4*>(
                    smw + (k * 4 + rsub) * 68 + l16 * 4);
                if (row < NNODE)
                    __builtin_nontemporal_store(h[k] + v,
                        reinterpret_cast<floatx4*>(out + (size_t)row * DMODEL + colf));
            }
        }
    }
}

// ---------------------------------------------------------------------------
extern "C" void kernel_launch(void* const* d_in, const int* in_sizes, int n_in,
                              void* d_out, int out_size, void* d_ws, size_t ws_size,
                              hipStream_t stream)
{
    const float* hidden   = (const float*)d_in[0];   // [20000][1024]
    const int*   ei       = (const int*)  d_in[1];   // [2][E]
    const int*   et       = (const int*)  d_in[2];   // [E]
    const float* ln_w     = (const float*)d_in[3];   // [1024]
    const float* W_rel    = (const float*)d_in[4];   // [2][1024][286]
    const float* W_root   = (const float*)d_in[5];   // [1024][286]
    const float* bias     = (const float*)d_in[6];   // [286]
    const float* wo       = (const float*)d_in[7];   // [286][1024]
    float* out = (float*)d_out;

    const int E = in_sizes[1] / 2;

    // workspace layout (bytes, 16B aligned)
    char* ws = (char*)d_ws;
    __bf16* norm_bf = (__bf16*)(ws + 0);            // 40,960,000
    __bf16* proj    = (__bf16*)(ws + 40960000);     // 34,560,000
    __bf16* y2      = (__bf16*)(ws + 75520000);     // 11,520,000
    __bf16* wroot_t = (__bf16*)(ws + 87040000);     // 589,824
    __bf16* wrel_t  = (__bf16*)(ws + 87629824);     // 1,179,648
    __bf16* wo_t    = (__bf16*)(ws + 88809472);     // 589,824
    int*    bcnt    = (int*)   (ws + 89399296);     // 80,000
    int*    boff    = (int*)   (ws + 89479296);     // 80,016
    int*    bcur    = (int*)   (ws + 89559312);     // 80,000
    int*    sorted  = (int*)   (ws + 89639312);     // 1,280,000

    hipMemsetAsync(bcnt, 0, 80000, stream);

    {
        dim3 g1((DMODEL + 31) / 32, (DFFP + 31) / 32);
        k_transpose_cast<<<g1, 256, 0, stream>>>(W_root, wroot_t, DMODEL, DFF, DMODEL, DFFP);
        k_transpose_cast<<<g1, 256, 0, stream>>>(W_rel, wrel_t, DMODEL, DFF, DMODEL, DFFP);
        k_transpose_cast<<<g1, 256, 0, stream>>>(W_rel + (size_t)DMODEL * DFF,
                                                 wrel_t + (size_t)DFFP * DMODEL,
                                                 DMODEL, DFF, DMODEL, DFFP);
        dim3 g2((DFFP + 31) / 32, (DMODEL + 31) / 32);
        k_transpose_cast<<<g2, 256, 0, stream>>>(wo, wo_t, DFF, DMODEL, DFFP, DMODEL);
    }

    k_rmsnorm<<<NNODE, 256, 0, stream>>>(hidden, ln_w, norm_bf);

    // edge sort
    k_hist<<<(E + 255) / 256, 256, 0, stream>>>(ei, bcnt, E);
    k_scan<<<1, 1024, 0, stream>>>(bcnt, boff, bcur);
    k_scatter_idx<<<(E + 255) / 256, 256, 0, stream>>>(ei, et, bcur, sorted, E);

    {
        int nmt = (NNODE + 127) / 128;   // 157
        k_gemm1<<<nmt * 3, 256, 0, stream>>>(norm_bf, wroot_t, wrel_t, proj);
    }

    k_reduce<<<NNODE / 4, 256, 0, stream>>>(boff, sorted, proj, bias, y2);

    {
        dim3 grid((NNODE + 127) / 128, DMODEL / 128);
        k_gemm2<<<grid, 256, 0, stream>>>(y2, wo_t, hidden, out);
    }
}

// Round 5
// 344.840 us; speedup vs baseline: 1.0213x; 1.0213x over previous
//
#include <hip/hip_runtime.h>
#include <hip/hip_bf16.h>

// ---------------------------------------------------------------------------
// N=20000 nodes, D_MODEL=1024, D_FF=286 (pad 288), NUM_REL=2, E=320000.
//
// Pipeline:
//   norm = rmsnorm(x) -> bf16
//   proj[z] = norm @ W_z   z in {root, rel0, rel1}   (bf16 MFMA, z-fastest,
//             XCD-grouped so z-triples share one L2; single-buffer staging,
//             BK=64: 16 barrier-drains, 72 MFMA/wave/step; slot-XOR LDS
//             swizzle -> conflict-free frag reads)
//   counting-sort edges by dst (hist -> scan -> cursor scatter)
//   per-dst wave: gather+sum proj_rel rows (unroll 4, branchless), mean+root
//                 +bias+ELU -> y2 (bf16)
//   out = hidden + y2 @ wo  (bf16 MFMA, dbuf staging; epilogue LDS-transposes
//         acc so residual add + store run as full-line float4 nt ops)
// ---------------------------------------------------------------------------

typedef __bf16  bf16x8  __attribute__((ext_vector_type(8)));
typedef float   floatx4 __attribute__((ext_vector_type(4)));

#define NNODE   20000
#define DMODEL  1024
#define DFF     286
#define DFFP    288
#define NDW     144     // dwords per padded row
#define NPAIR   72      // uint2 per padded row

typedef __attribute__((address_space(1))) const void* gptr_t;
typedef __attribute__((address_space(3))) void*       lptr_t;

struct alignas(8) bf4 { __bf16 x, y, z, w; };

__device__ __forceinline__ float bflo(unsigned u) {
    union { unsigned u; float f; } c; c.u = u << 16; return c.f;
}
__device__ __forceinline__ float bfhi(unsigned u) {
    union { unsigned u; float f; } c; c.u = u & 0xffff0000u; return c.f;
}
__device__ __forceinline__ unsigned packbf(float a, float b) {
    union { __bf16 h[2]; unsigned u; } c;
    c.h[0] = (__bf16)a; c.h[1] = (__bf16)b; return c.u;
}
__device__ __forceinline__ float elu1(float v) {
    return v > 0.0f ? v : (expf(v) - 1.0f);
}

// ---------------------------------------------------------------------------
// K0: tiled transpose + cast fp32 [K][N] -> bf16 [Nout][Kout], zero-padded.
// ---------------------------------------------------------------------------
__global__ __launch_bounds__(256) void k_transpose_cast(
    const float* __restrict__ src, __bf16* __restrict__ dst,
    int K, int N, int Kout, int Nout)
{
    __shared__ float t[32][33];
    int tx = threadIdx.x & 31, ty = threadIdx.x >> 5;
    int k0 = blockIdx.x * 32, n0 = blockIdx.y * 32;
    #pragma unroll
    for (int r = 0; r < 4; ++r) {
        int k = k0 + ty + r * 8, n = n0 + tx;
        t[ty + r * 8][tx] = (k < K && n < N) ? src[(size_t)k * N + n] : 0.0f;
    }
    __syncthreads();
    #pragma unroll
    for (int r = 0; r < 4; ++r) {
        int n = n0 + ty + r * 8, k = k0 + tx;
        if (n < Nout && k < Kout) dst[(size_t)n * Kout + k] = (__bf16)t[tx][ty + r * 8];
    }
}

// ---------------------------------------------------------------------------
// K1: T5 RMSNorm, one block (256 thr) per row, float4 loads, bf16 out.
// ---------------------------------------------------------------------------
__global__ __launch_bounds__(256) void k_rmsnorm(
    const float* __restrict__ x, const float* __restrict__ w,
    __bf16* __restrict__ out)
{
    int row = blockIdx.x;
    int t = threadIdx.x;
    float4 v = reinterpret_cast<const float4*>(x + (size_t)row * DMODEL)[t];
    float ss = v.x * v.x + v.y * v.y + v.z * v.z + v.w * v.w;
    #pragma unroll
    for (int off = 32; off; off >>= 1) ss += __shfl_down(ss, off, 64);
    __shared__ float red[4];
    int lane = t & 63, wv = t >> 6;
    if (lane == 0) red[wv] = ss;
    __syncthreads();
    float tot = red[0] + red[1] + red[2] + red[3];
    float scale = rsqrtf(tot * (1.0f / (float)DMODEL) + 1e-6f);
    float4 wv4 = reinterpret_cast<const float4*>(w)[t];
    bf4 o;
    o.x = (__bf16)(v.x * scale * wv4.x);
    o.y = (__bf16)(v.y * scale * wv4.y);
    o.z = (__bf16)(v.z * scale * wv4.z);
    o.w = (__bf16)(v.w * scale * wv4.w);
    reinterpret_cast<bf4*>(out + (size_t)row * DMODEL)[t] = o;
}

// ---------------------------------------------------------------------------
// K2: GEMM1  proj[z] = norm @ B_z.   A:[20000][1024] bf16, B^T:[288][1024].
// Block = 128(M) x 288(N) for one z; 1-D grid, z fastest; bijective XCD
// swizzle groups z-triples on one XCD (A L2 reuse).
// 4 waves 2x2; wave-tile 64x144. BK=64: 16 K-steps, 72 MFMA/wave/step --
// halves the per-step barrier-drain count vs BK=32 (latency amortization).
// SINGLE-buffered 2-barrier staging (R3 showed merged-barrier dbuf loses:
// hipcc's vmcnt(0)-before-barrier drains the prefetch anyway).
// LDS layout: row = 64 bf16 = 8 x 16B slots; chunks are 8-row aligned so
// stored slot = (lane&7)^(lane>>3) on the GLOBAL source (dest stays linear,
// Rule 21); reads XOR logical slot with (row&7)=(l16&7) -> 2-way only.
// ---------------------------------------------------------------------------
__global__ __launch_bounds__(256, 2) void k_gemm1(
    const __bf16* __restrict__ A, const __bf16* __restrict__ Broot,
    const __bf16* __restrict__ Brel, __bf16* __restrict__ P)
{
    // bijective XCD swizzle (nwg = 471, not a multiple of 8)
    const int nwg = gridDim.x;
    const int q = nwg >> 3, r = nwg & 7;
    const int xcd = blockIdx.x & 7, sub = blockIdx.x >> 3;
    const int bid = (xcd < r ? xcd * (q + 1) : r * (q + 1) + (xcd - r) * q) + sub;

    const int mt = bid / 3, mz = bid - mt * 3;
    const __bf16* B = (mz == 0) ? Broot : (Brel + (size_t)(mz - 1) * DFFP * DMODEL);
    __bf16* out = P + (size_t)mz * NNODE * DFFP;

    const int m0 = mt * 128;
    const int tid = threadIdx.x;
    const int lane = tid & 63, wave = tid >> 6;
    const int wm = wave >> 1, wn = wave & 1;
    const int quad = lane >> 4, l16 = lane & 15;

    __shared__ __align__(16) __bf16 As[128 * 64];   // 16 KB
    __shared__ __align__(16) __bf16 Bs[288 * 64];   // 36 KB

    floatx4 zero = {0.f, 0.f, 0.f, 0.f};
    floatx4 acc[4][9];
    #pragma unroll
    for (int i = 0; i < 4; ++i)
        #pragma unroll
        for (int j = 0; j < 9; ++j) acc[i][j] = zero;

    const int crow = lane >> 3;                      // row within 8-row chunk
    const int sl   = ((lane & 7) ^ (lane >> 3)) * 8; // swizzled slot, source (bf16)
    const int sq0  = ((quad)     ^ (l16 & 7)) * 8;   // swizzled read slot, kfrag 0
    const int sq1  = ((quad + 4) ^ (l16 & 7)) * 8;   // swizzled read slot, kfrag 1

    for (int k0 = 0; k0 < DMODEL; k0 += 64) {
        // 52 chunks of 8 rows x 64 cols (A:16, B:36); 13 per wave.
        #pragma unroll
        for (int ii = 0; ii < 13; ++ii) {
            int c = wave + ii * 4;
            if (c < 16) {
                int grow = m0 + c * 8 + crow; if (grow > NNODE - 1) grow = NNODE - 1;
                __builtin_amdgcn_global_load_lds(
                    (gptr_t)(A + (size_t)grow * DMODEL + k0 + sl),
                    (lptr_t)(As + c * 512), 16, 0, 0);
            } else {
                int nrow = (c - 16) * 8 + crow;
                __builtin_amdgcn_global_load_lds(
                    (gptr_t)(B + (size_t)nrow * DMODEL + k0 + sl),
                    (lptr_t)(Bs + (c - 16) * 512), 16, 0, 0);
            }
        }
        __syncthreads();
        #pragma unroll
        for (int f = 0; f < 2; ++f) {
            const int sq = f ? sq1 : sq0;
            bf16x8 af[4], bq[9];
            #pragma unroll
            for (int i = 0; i < 4; ++i)
                af[i] = *reinterpret_cast<const bf16x8*>(As + (wm * 64 + i * 16 + l16) * 64 + sq);
            #pragma unroll
            for (int j = 0; j < 9; ++j)
                bq[j] = *reinterpret_cast<const bf16x8*>(Bs + (wn * 144 + j * 16 + l16) * 64 + sq);
            #pragma unroll
            for (int i = 0; i < 4; ++i)
                #pragma unroll
                for (int j = 0; j < 9; ++j)
                    acc[i][j] = __builtin_amdgcn_mfma_f32_16x16x32_bf16(af[i], bq[j], acc[i][j], 0, 0, 0);
        }
        __syncthreads();
    }
    #pragma unroll
    for (int i = 0; i < 4; ++i) {
        int rbase = m0 + wm * 64 + i * 16 + quad * 4;
        #pragma unroll
        for (int j = 0; j < 9; ++j) {
            int col = wn * 144 + j * 16 + l16;
            #pragma unroll
            for (int rr = 0; rr < 4; ++rr) {
                int row = rbase + rr;
                if (row < NNODE) out[(size_t)row * DFFP + col] = (__bf16)acc[i][j][rr];
            }
        }
    }
}

// ---------------------------------------------------------------------------
// K3a: histogram of edges by dst.
// ---------------------------------------------------------------------------
__global__ __launch_bounds__(256) void k_hist(
    const int* __restrict__ ei, int* __restrict__ bcnt, int E)
{
    int t = blockIdx.x * 256 + threadIdx.x;
    if (t < E) atomicAdd(&bcnt[ei[E + t]], 1);
}

// ---------------------------------------------------------------------------
// K3b: exclusive scan over 20000 bucket counts (single block, 1024 thr).
// ---------------------------------------------------------------------------
__global__ __launch_bounds__(1024) void k_scan(
    const int* __restrict__ bcnt, int* __restrict__ boff, int* __restrict__ bcur)
{
    const int CH = 20;
    __shared__ int s[1024];
    int t = threadIdx.x;
    int base = t * CH;
    int loc[CH];
    int sum = 0;
    #pragma unroll
    for (int i = 0; i < CH; ++i) {
        int idx = base + i;
        int v = (idx < NNODE) ? bcnt[idx] : 0;
        loc[i] = sum; sum += v;
    }
    s[t] = sum;
    __syncthreads();
    for (int off = 1; off < 1024; off <<= 1) {
        int v = (t >= off) ? s[t - off] : 0;
        __syncthreads();
        s[t] += v;
        __syncthreads();
    }
    int prev = (t == 0) ? 0 : s[t - 1];
    #pragma unroll
    for (int i = 0; i < CH; ++i) {
        int idx = base + i;
        if (idx < NNODE) { int o = prev + loc[i]; boff[idx] = o; bcur[idx] = o; }
    }
    if (t == 1023) boff[NNODE] = s[1023];
}

// ---------------------------------------------------------------------------
// K3c: scatter edges into sorted order; payload = src | (r<<20).
// ---------------------------------------------------------------------------
__global__ __launch_bounds__(256) void k_scatter_idx(
    const int* __restrict__ ei, const int* __restrict__ et,
    int* __restrict__ bcur, int* __restrict__ sorted, int E)
{
    int t = blockIdx.x * 256 + threadIdx.x;
    if (t >= E) return;
    int src = ei[t], dst = ei[E + t], r = et[t];
    int pos = atomicAdd(&bcur[dst], 1);
    sorted[pos] = src | (r << 20);
}

// ---------------------------------------------------------------------------
// K4: segment reduce + epilogue. One wave per dst node; uint2 gathers,
// edge loop unrolled x4 (8 gathers in flight), branchless accumulate.
// ---------------------------------------------------------------------------
__global__ __launch_bounds__(256) void k_reduce(
    const int* __restrict__ boff, const int* __restrict__ sorted,
    const __bf16* __restrict__ proj, const float* __restrict__ bias,
    __bf16* __restrict__ y2)
{
    int b = blockIdx.x * 4 + (threadIdx.x >> 6);
    int lane = threadIdx.x & 63;
    int start = boff[b], end = boff[b + 1];
    bool t8 = lane < 8;

    const uint2* base1 = reinterpret_cast<const uint2*>(proj + (size_t)NNODE * DFFP);
    const size_t relstride = (size_t)NNODE * NPAIR;

    float a0[4] = {0.f, 0.f, 0.f, 0.f}, b0a[4] = {0.f, 0.f, 0.f, 0.f};
    float a1[4] = {0.f, 0.f, 0.f, 0.f}, b1a[4] = {0.f, 0.f, 0.f, 0.f};
    float c0 = 0.f, c1 = 0.f;
    uint2 zz; zz.x = 0u; zz.y = 0u;

    int e = start;
    for (; e + 4 <= end; e += 4) {
        uint2 x[4], y[4]; float w1[4];
        #pragma unroll
        for (int u = 0; u < 4; ++u) {
            int p = sorted[e + u];
            int ri = p >> 20;
            w1[u] = (float)ri;
            const uint2* row = base1 + (size_t)(p & 0xFFFFF) * NPAIR + (ri ? relstride : 0);
            x[u] = row[lane];
            y[u] = t8 ? row[64 + lane] : zz;
        }
        #pragma unroll
        for (int u = 0; u < 4; ++u) {
            float W1 = w1[u], W0 = 1.0f - W1;
            c0 += W0; c1 += W1;
            float v0 = bflo(x[u].x), v1 = bfhi(x[u].x), v2 = bflo(x[u].y), v3 = bfhi(x[u].y);
            a0[0] += W0 * v0; a1[0] += W1 * v0;
            a0[1] += W0 * v1; a1[1] += W1 * v1;
            a0[2] += W0 * v2; a1[2] += W1 * v2;
            a0[3] += W0 * v3; a1[3] += W1 * v3;
            float u0 = bflo(y[u].x), u1 = bfhi(y[u].x), u2 = bflo(y[u].y), u3 = bfhi(y[u].y);
            b0a[0] += W0 * u0; b1a[0] += W1 * u0;
            b0a[1] += W0 * u1; b1a[1] += W1 * u1;
            b0a[2] += W0 * u2; b1a[2] += W1 * u2;
            b0a[3] += W0 * u3; b1a[3] += W1 * u3;
        }
    }
    for (; e < end; ++e) {
        int p = sorted[e];
        int ri = p >> 20;
        float W1 = (float)ri, W0 = 1.0f - W1;
        const uint2* row = base1 + (size_t)(p & 0xFFFFF) * NPAIR + (ri ? relstride : 0);
        uint2 x = row[lane];
        uint2 y = t8 ? row[64 + lane] : zz;
        c0 += W0; c1 += W1;
        float v0 = bflo(x.x), v1 = bfhi(x.x), v2 = bflo(x.y), v3 = bfhi(x.y);
        a0[0] += W0 * v0; a1[0] += W1 * v0;
        a0[1] += W0 * v1; a1[1] += W1 * v1;
        a0[2] += W0 * v2; a1[2] += W1 * v2;
        a0[3] += W0 * v3; a1[3] += W1 * v3;
        float u0 = bflo(y.x), u1 = bfhi(y.x), u2 = bflo(y.y), u3 = bfhi(y.y);
        b0a[0] += W0 * u0; b1a[0] += W1 * u0;
        b0a[1] += W0 * u1; b1a[1] += W1 * u1;
        b0a[2] += W0 * u2; b1a[2] += W1 * u2;
        b0a[3] += W0 * u3; b1a[3] += W1 * u3;
    }

    float inv0 = 1.0f / fmaxf(c0, 1.0f);
    float inv1 = 1.0f / fmaxf(c1, 1.0f);

    const uint2* rootrow = reinterpret_cast<const uint2*>(proj) + (size_t)b * NPAIR;
    uint2* outrow = reinterpret_cast<uint2*>(y2) + (size_t)b * NPAIR;

    {
        uint2 rt = rootrow[lane];
        int f = 4 * lane;                 // max 255 < 286: no guard
        float v0 = bflo(rt.x) + bias[f]     + a0[0] * inv0 + a1[0] * inv1;
        float v1 = bfhi(rt.x) + bias[f + 1] + a0[1] * inv0 + a1[1] * inv1;
        float v2 = bflo(rt.y) + bias[f + 2] + a0[2] * inv0 + a1[2] * inv1;
        float v3 = bfhi(rt.y) + bias[f + 3] + a0[3] * inv0 + a1[3] * inv1;
        uint2 o; o.x = packbf(elu1(v0), elu1(v1)); o.y = packbf(elu1(v2), elu1(v3));
        outrow[lane] = o;
    }
    if (t8) {
        uint2 rt = rootrow[64 + lane];
        int f = 256 + 4 * lane;           // 256..287: guard vs 286
        float g0 = (f     < DFF) ? bias[f]     : 0.0f;
        float g1 = (f + 1 < DFF) ? bias[f + 1] : 0.0f;
        float g2 = (f + 2 < DFF) ? bias[f + 2] : 0.0f;
        float g3 = (f + 3 < DFF) ? bias[f + 3] : 0.0f;
        float v0 = bflo(rt.x) + g0 + b0a[0] * inv0 + b1a[0] * inv1;
        float v1 = bfhi(rt.x) + g1 + b0a[1] * inv0 + b1a[1] * inv1;
        float v2 = bflo(rt.y) + g2 + b0a[2] * inv0 + b1a[2] * inv1;
        float v3 = bfhi(rt.y) + g3 + b0a[3] * inv0 + b1a[3] * inv1;
        uint2 o; o.x = packbf(elu1(v0), elu1(v1)); o.y = packbf(elu1(v2), elu1(v3));
        outrow[64 + lane] = o;
    }
}

// ---------------------------------------------------------------------------
// K5: GEMM2  out = hidden + y2 @ wo.  A:[20000][288] bf16, B^T:[1024][288].
// Tile 128x128; 4 waves 2x2; wave-tile 64x64 = 4x4 MFMAs. 9 K-steps,
// double-buffered global_load_lds staging; slot-XOR LDS swizzle.
// Epilogue: per 16-row chunk, each wave scatters its acc into a private
// padded LDS region, reads back float4-per-lane, then residual add with
// float4 nontemporal loads/stores -> 256B contiguous, full-128B-line writes.
// ---------------------------------------------------------------------------
__global__ __launch_bounds__(256) void k_gemm2(
    const __bf16* __restrict__ A, const __bf16* __restrict__ Bt,
    const float* __restrict__ hidden, float* __restrict__ out)
{
    const int m0 = blockIdx.x * 128;
    const int n0 = blockIdx.y * 128;
    const int tid = threadIdx.x;
    const int lane = tid & 63, wave = tid >> 6;
    const int wm = wave >> 1, wn = wave & 1;
    const int quad = lane >> 4, l16 = lane & 15;

    __shared__ __align__(16) __bf16 As[2][128 * 32];   // 2 x 8 KB
    __shared__ __align__(16) __bf16 Bs[2][128 * 32];   // 2 x 8 KB

    floatx4 zero = {0.f, 0.f, 0.f, 0.f};
    floatx4 acc[4][4];
    #pragma unroll
    for (int i = 0; i < 4; ++i)
        #pragma unroll
        for (int j = 0; j < 4; ++j) acc[i][j] = zero;

    const int crow = lane >> 2;
    const int ccol = ((lane & 3) ^ ((lane >> 3) & 3)) * 8;   // swizzled K-slot source
    const int sq   = (quad ^ ((l16 >> 1) & 3)) * 8;          // swizzled K-slot read

    auto stage = [&](int kk, int buf) {
        #pragma unroll
        for (int ii = 0; ii < 4; ++ii) {
            int c = wave + ii * 4;
            if (c < 8) {
                int grow = m0 + c * 16 + crow; if (grow > NNODE - 1) grow = NNODE - 1;
                __builtin_amdgcn_global_load_lds(
                    (gptr_t)(A + (size_t)grow * DFFP + kk + ccol),
                    (lptr_t)(As[buf] + c * 512), 16, 0, 0);
            } else {
                int nrow = n0 + (c - 8) * 16 + crow;
                __builtin_amdgcn_global_load_lds(
                    (gptr_t)(Bt + (size_t)nrow * DFFP + kk + ccol),
                    (lptr_t)(Bs[buf] + (c - 8) * 512), 16, 0, 0);
            }
        }
    };

    stage(0, 0);
    __syncthreads();
    for (int ks = 0; ks < 9; ++ks) {
        int buf = ks & 1;
        if (ks < 8) stage((ks + 1) * 32, buf ^ 1);
        bf16x8 af[4], bq[4];
        #pragma unroll
        for (int i = 0; i < 4; ++i)
            af[i] = *reinterpret_cast<const bf16x8*>(As[buf] + (wm * 64 + i * 16 + l16) * 32 + sq);
        #pragma unroll
        for (int j = 0; j < 4; ++j)
            bq[j] = *reinterpret_cast<const bf16x8*>(Bs[buf] + (wn * 64 + j * 16 + l16) * 32 + sq);
        #pragma unroll
        for (int i = 0; i < 4; ++i)
            #pragma unroll
            for (int j = 0; j < 4; ++j)
                acc[i][j] = __builtin_amdgcn_mfma_f32_16x16x32_bf16(af[i], bq[j], acc[i][j], 0, 0, 0);
        __syncthreads();
    }

    // --- epilogue: LDS transpose -> float4 residual add, full-line nt I/O ---
    {
        float* smbase = reinterpret_cast<float*>(wave < 2 ? (__bf16*)As[0] : (__bf16*)Bs[0]);
        float* smw = smbase + (wave & 1) * 1088;         // 1088 = 16*68
        const int rsub = lane >> 4;                       // 0..3
        const int colf = n0 + wn * 64 + l16 * 4;          // 4 consecutive cols/lane
        #pragma unroll
        for (int i = 0; i < 4; ++i) {
            #pragma unroll
            for (int j = 0; j < 4; ++j)
                #pragma unroll
                for (int rr = 0; rr < 4; ++rr)
                    smw[(quad * 4 + rr) * 68 + j * 16 + l16] = acc[i][j][rr];
            const int rbase = m0 + wm * 64 + i * 16;
            floatx4 h[4];
            #pragma unroll
            for (int k = 0; k < 4; ++k) {
                int row = rbase + k * 4 + rsub;
                if (row > NNODE - 1) row = NNODE - 1;
                h[k] = __builtin_nontemporal_load(
                    reinterpret_cast<const floatx4*>(hidden + (size_t)row * DMODEL + colf));
            }
            #pragma unroll
            for (int k = 0; k < 4; ++k) {
                int row = rbase + k * 4 + rsub;
                floatx4 v = *reinterpret_cast<const floatx4*>(
                    smw + (k * 4 + rsub) * 68 + l16 * 4);
                if (row < NNODE)
                    __builtin_nontemporal_store(h[k] + v,
                        reinterpret_cast<floatx4*>(out + (size_t)row * DMODEL + colf));
            }
        }
    }
}

// ---------------------------------------------------------------------------
extern "C" void kernel_launch(void* const* d_in, const int* in_sizes, int n_in,
                              void* d_out, int out_size, void* d_ws, size_t ws_size,
                              hipStream_t stream)
{
    const float* hidden   = (const float*)d_in[0];   // [20000][1024]
    const int*   ei       = (const int*)  d_in[1];   // [2][E]
    const int*   et       = (const int*)  d_in[2];   // [E]
    const float* ln_w     = (const float*)d_in[3];   // [1024]
    const float* W_rel    = (const float*)d_in[4];   // [2][1024][286]
    const float* W_root   = (const float*)d_in[5];   // [1024][286]
    const float* bias     = (const float*)d_in[6];   // [286]
    const float* wo       = (const float*)d_in[7];   // [286][1024]
    float* out = (float*)d_out;

    const int E = in_sizes[1] / 2;

    // workspace layout (bytes, 16B aligned)
    char* ws = (char*)d_ws;
    __bf16* norm_bf = (__bf16*)(ws + 0);            // 40,960,000
    __bf16* proj    = (__bf16*)(ws + 40960000);     // 34,560,000
    __bf16* y2      = (__bf16*)(ws + 75520000);     // 11,520,000
    __bf16* wroot_t = (__bf16*)(ws + 87040000);     // 589,824
    __bf16* wrel_t  = (__bf16*)(ws + 87629824);     // 1,179,648
    __bf16* wo_t    = (__bf16*)(ws + 88809472);     // 589,824
    int*    bcnt    = (int*)   (ws + 89399296);     // 80,000
    int*    boff    = (int*)   (ws + 89479296);     // 80,016
    int*    bcur    = (int*)   (ws + 89559312);     // 80,000
    int*    sorted  = (int*)   (ws + 89639312);     // 1,280,000

    hipMemsetAsync(bcnt, 0, 80000, stream);

    {
        dim3 g1((DMODEL + 31) / 32, (DFFP + 31) / 32);
        k_transpose_cast<<<g1, 256, 0, stream>>>(W_root, wroot_t, DMODEL, DFF, DMODEL, DFFP);
        k_transpose_cast<<<g1, 256, 0, stream>>>(W_rel, wrel_t, DMODEL, DFF, DMODEL, DFFP);
        k_transpose_cast<<<g1, 256, 0, stream>>>(W_rel + (size_t)DMODEL * DFF,
                                                 wrel_t + (size_t)DFFP * DMODEL,
                                                 DMODEL, DFF, DMODEL, DFFP);
        dim3 g2((DFFP + 31) / 32, (DMODEL + 31) / 32);
        k_transpose_cast<<<g2, 256, 0, stream>>>(wo, wo_t, DFF, DMODEL, DFFP, DMODEL);
    }

    k_rmsnorm<<<NNODE, 256, 0, stream>>>(hidden, ln_w, norm_bf);

    // edge sort
    k_hist<<<(E + 255) / 256, 256, 0, stream>>>(ei, bcnt, E);
    k_scan<<<1, 1024, 0, stream>>>(bcnt, boff, bcur);
    k_scatter_idx<<<(E + 255) / 256, 256, 0, stream>>>(ei, et, bcur, sorted, E);

    {
        int nmt = (NNODE + 127) / 128;   // 157
        k_gemm1<<<nmt * 3, 256, 0, stream>>>(norm_bf, wroot_t, wrel_t, proj);
    }

    k_reduce<<<NNODE / 4, 256, 0, stream>>>(boff, sorted, proj, bias, y2);

    {
        dim3 grid((NNODE + 127) / 128, DMODEL / 128);
        k_gemm2<<<grid, 256, 0, stream>>>(y2, wo_t, hidden, out);
    }
}